// Round 1
// baseline (500.429 us; speedup 1.0000x reference)
//
#include <hip/hip_runtime.h>

#define N_NODES 100000
#define N_EDGES 1600000
#define IN_DIM 256
#define HID 64
#define N_GRAPHS 100
#define BSHIFT 8
#define NBUCK 391   // ceil(N_NODES / 256) == ceil(N_EDGES / CHUNK)
#define CHUNK 4096  // edges per block in bucket passes

typedef __attribute__((ext_vector_type(8))) short short8;
typedef __attribute__((ext_vector_type(8))) unsigned short us8;
typedef __attribute__((ext_vector_type(4))) float floatx4;

// bf16 helpers (RNE)
__device__ __forceinline__ unsigned short f2b(float f) {
    unsigned int u = __float_as_uint(f);
    unsigned int r = (u + 0x7FFFu + ((u >> 16) & 1u)) >> 16;
    return (unsigned short)r;
}
__device__ __forceinline__ float b2f(unsigned short b) {
    return __uint_as_float(((unsigned int)b) << 16);
}

// ---------------- prep: W transpose/bf16, w3l = W3@Wl, zero counters ----------------

__global__ void k_prep(const float* __restrict__ W1, const float* __restrict__ W2,
                       const float* __restrict__ W3, const float* __restrict__ Wl,
                       const float* __restrict__ b3,
                       unsigned short* __restrict__ wt1, unsigned short* __restrict__ wt2,
                       float* __restrict__ w3l,
                       int* __restrict__ bcount, int* __restrict__ bfillrel,
                       float* __restrict__ partial, int* __restrict__ bar) {
    int i = blockIdx.x * 256 + threadIdx.x;
    if (i < IN_DIM * HID) {
        int k = i >> 6, n = i & 63;
        wt1[n * IN_DIM + k] = f2b(W1[i]);
    }
    if (i < HID * HID) {
        int k = i >> 6, n = i & 63;
        wt2[n * HID + k] = f2b(W2[i]);
    }
    if (i < NBUCK) { bcount[i] = 0; bfillrel[i] = 0; }
    if (i < N_GRAPHS * 256) partial[i] = 0.f;
    if (i < 8) bar[i] = 0;
    if (blockIdx.x == 0) {
        int t = threadIdx.x;
        if (t < HID) {
            float s = 0.f;
            for (int n = 0; n < HID; ++n) s += W3[t * HID + n] * Wl[n];
            w3l[t] = s;
        } else if (t == HID) {
            float s = 0.f;
            for (int n = 0; n < HID; ++n) s += b3[n] * Wl[n];
            w3l[HID] = s;  // b3wl
        }
    }
}

// ---------------- fused CSR build (persistent grid, software barriers) ----------------

__device__ __forceinline__ void grid_bar(int* cnt) {
    __syncthreads();
    if (threadIdx.x == 0) {
        __threadfence();  // release: drain + write back this XCD's dirty lines
        atomicAdd(cnt, 1);
        while (__hip_atomic_load(cnt, __ATOMIC_RELAXED, __HIP_MEMORY_SCOPE_AGENT) < NBUCK)
            __builtin_amdgcn_s_sleep(2);
        __threadfence();  // acquire: invalidate stale L1/L2 lines
    }
    __syncthreads();
}

// inclusive scan of 512 ints held in sA (sB = ping-pong buffer); returns result ptr
__device__ __forceinline__ int* scan512(int* sA, int* sB, int t) {
    int* A = sA;
    int* B = sB;
    for (int off = 1; off < 512; off <<= 1) {
        B[t] = A[t] + ((t >= off) ? A[t - off] : 0);
        B[t + 256] = A[t + 256] + A[t + 256 - off];
        __syncthreads();
        int* tmp = A; A = B; B = tmp;
    }
    return A;
}

__global__ __launch_bounds__(256) void k_setup(const int* __restrict__ src,
                                               const int* __restrict__ dstp,
                                               int* __restrict__ bcount,
                                               int* __restrict__ bfillrel,
                                               int* __restrict__ ebuck,
                                               int* __restrict__ deg,
                                               float* __restrict__ dinv,
                                               int* __restrict__ bsum,
                                               int* __restrict__ rowptr,
                                               int* __restrict__ col,
                                               int* __restrict__ bar) {
    __shared__ int lc[NBUCK];        // chunk histogram, then scatter bases
    __shared__ int ebst[NBUCK + 1];  // bucket starts (exclusive scan of bcount)
    __shared__ int sA[512];
    __shared__ int sB[512];
    __shared__ int ld[256];
    __shared__ int lf[256];
    const int b = blockIdx.x, t = threadIdx.x;

    // ---- phase A: chunk histogram + per-edge ranks (single src/dst read) ----
    for (int i = t; i < NBUCK; i += 256) lc[i] = 0;
    __syncthreads();
    const int base = b * CHUNK;
    int pk[16], bk[16], rk[16];
#pragma unroll
    for (int i = 0; i < 16; ++i) {
        int e = base + i * 256 + t;
        rk[i] = -1;
        if (e < N_EDGES) {
            int s = src[e], d = dstp[e];
            bk[i] = d >> BSHIFT;
            pk[i] = (s << BSHIFT) | (d & 255);
            rk[i] = atomicAdd(&lc[bk[i]], 1);
        }
    }
    __syncthreads();
    for (int i = t; i < NBUCK; i += 256)
        if (lc[i]) atomicAdd(&bcount[i], lc[i]);

    grid_bar(bar + 0);

    // ---- phase B: every block scans bcount -> ebst (identical result) ----
    {
        int v0 = (t < NBUCK) ? bcount[t] : 0;
        int v1 = (t + 256 < NBUCK) ? bcount[t + 256] : 0;
        sA[t] = v0;
        sA[t + 256] = v1;
        __syncthreads();
        int* A = scan512(sA, sB, t);
        if (t < NBUCK) ebst[t] = A[t] - v0;
        if (t + 256 < NBUCK) ebst[t + 256] = A[t + 256] - v1;
        if (t == 0) ebst[NBUCK] = N_EDGES;
        __syncthreads();
    }

    // ---- phase C: scatter edges into buckets ----
    for (int i = t; i < NBUCK; i += 256)
        lc[i] = lc[i] ? (ebst[i] + atomicAdd(&bfillrel[i], lc[i])) : 0;
    __syncthreads();
#pragma unroll
    for (int i = 0; i < 16; ++i)
        if (rk[i] >= 0) ebuck[lc[bk[i]] + rk[i]] = pk[i];

    grid_bar(bar + 1);

    // ---- phase D: per-bucket degree histogram + dinv + bucket sum of (deg-1) ----
    const int bs = ebst[b], be = ebst[b + 1];
    ld[t] = 1;  // self loop
    __syncthreads();
    for (int j = bs + t; j < be; j += 256) atomicAdd(&ld[ebuck[j] & 255], 1);
    __syncthreads();
    const int node = (b << BSHIFT) + t;
    const int dg = ld[t];
    if (node < N_NODES) {
        deg[node] = dg;
        dinv[node] = rsqrtf((float)dg);
    }
    sA[t] = (node < N_NODES) ? dg - 1 : 0;
    __syncthreads();
    for (int off = 128; off; off >>= 1) {
        if (t < off) sA[t] += sA[t + off];
        __syncthreads();
    }
    if (t == 0) bsum[b] = sA[0];

    grid_bar(bar + 2);

    // ---- phase E: global rowptr offsets + in-bucket scan + CSR col fill ----
    {
        sA[t] = (t < NBUCK) ? bsum[t] : 0;
        sA[t + 256] = (t + 256 < NBUCK) ? bsum[t + 256] : 0;
        __syncthreads();
        int* A = scan512(sA, sB, t);  // A == sB after 9 iterations
        const int off_b = (b > 0) ? A[b - 1] : 0;  // exclusive bucket offset
        __syncthreads();
        // in-bucket exclusive scan of (deg-1) over 256 nodes
        int c = (node < N_NODES) ? dg - 1 : 0;
        sA[t] = c;
        __syncthreads();
        for (int off = 1; off < 256; off <<= 1) {
            int u = 0;
            if (t >= off) u = sA[t - off];
            __syncthreads();
            sA[t] += u;
            __syncthreads();
        }
        const int pos = off_b + sA[t] - c;
        if (node < N_NODES) rowptr[node] = pos;
        lf[t] = pos;
        __syncthreads();
        for (int j = bs + t; j < be; j += 256) {
            int v = ebuck[j];
            int p = atomicAdd(&lf[v & 255], 1);
            col[p] = v >> BSHIFT;
        }
    }
}

// ---------------- MFMA GEMM1: Tb = dinv * (X[fp32] @ W1) ----------------

__global__ __launch_bounds__(256) void k_gemm1(const float* __restrict__ X,
                                               const unsigned short* __restrict__ Wt,
                                               const float* __restrict__ dinv,
                                               unsigned short* __restrict__ Tb) {
    __shared__ unsigned short Wb[64][264];
    const int t = threadIdx.x;
    const int lane = t & 63, wv = t >> 6;
    const int fl = lane & 15, quad = lane >> 4;
    const int r0 = blockIdx.x * 64;

    for (int g = t; g < 64 * 32; g += 256) {
        int n = g >> 5, kc8 = g & 31;
        *(us8*)&Wb[n][kc8 * 8] = *(const us8*)(Wt + n * IN_DIM + kc8 * 8);
    }

    const int arow = r0 + wv * 16 + fl;
    const bool valid = arow < N_NODES;
    const float* xp = X + (size_t)(valid ? arow : 0) * IN_DIM;

    floatx4 acc[4];
#pragma unroll
    for (int j = 0; j < 4; ++j) acc[j] = (floatx4){0.f, 0.f, 0.f, 0.f};

    __syncthreads();

#pragma unroll
    for (int kc = 0; kc < IN_DIM; kc += 32) {
        float4 x0 = make_float4(0.f, 0.f, 0.f, 0.f);
        float4 x1 = make_float4(0.f, 0.f, 0.f, 0.f);
        if (valid) {
            x0 = *(const float4*)(xp + kc + quad * 8);
            x1 = *(const float4*)(xp + kc + quad * 8 + 4);
        }
        short8 a;
        a[0] = (short)f2b(x0.x); a[1] = (short)f2b(x0.y);
        a[2] = (short)f2b(x0.z); a[3] = (short)f2b(x0.w);
        a[4] = (short)f2b(x1.x); a[5] = (short)f2b(x1.y);
        a[6] = (short)f2b(x1.z); a[7] = (short)f2b(x1.w);
#pragma unroll
        for (int ct = 0; ct < 4; ++ct) {
            short8 b = *(const short8*)&Wb[ct * 16 + fl][kc + quad * 8];
            acc[ct] = __builtin_amdgcn_mfma_f32_16x16x32_bf16(a, b, acc[ct], 0, 0, 0);
        }
    }

    int rbase = r0 + wv * 16 + quad * 4;
#pragma unroll
    for (int r = 0; r < 4; ++r) {
        int row = rbase + r;
        if (row < N_NODES) {
            float di = dinv[row];
#pragma unroll
            for (int ct = 0; ct < 4; ++ct)
                Tb[(size_t)row * HID + ct * 16 + fl] = f2b(di * acc[ct][r]);
        }
    }
}

// ---------------- MFMA GEMM2: Tb = dinv * (Hb[bf16] @ W) ----------------

__global__ __launch_bounds__(256) void k_gemm2(const unsigned short* __restrict__ Xin,
                                               const unsigned short* __restrict__ Wt,
                                               const float* __restrict__ dinv,
                                               unsigned short* __restrict__ Tb) {
    __shared__ unsigned short Wb[64][72];
    const int t = threadIdx.x;
    const int lane = t & 63, wv = t >> 6;
    const int fl = lane & 15, quad = lane >> 4;
    const int r0 = blockIdx.x * 64;

    for (int g = t; g < 64 * 8; g += 256) {
        int n = g >> 3, kc8 = g & 7;
        *(us8*)&Wb[n][kc8 * 8] = *(const us8*)(Wt + n * HID + kc8 * 8);
    }

    const int arow = r0 + wv * 16 + fl;
    const bool valid = arow < N_NODES;
    const unsigned short* xp = Xin + (size_t)(valid ? arow : 0) * HID;

    floatx4 acc[4];
#pragma unroll
    for (int j = 0; j < 4; ++j) acc[j] = (floatx4){0.f, 0.f, 0.f, 0.f};

    __syncthreads();

#pragma unroll
    for (int kc = 0; kc < HID; kc += 32) {
        short8 a = (short8){0, 0, 0, 0, 0, 0, 0, 0};
        if (valid) a = *(const short8*)(xp + kc + quad * 8);
#pragma unroll
        for (int ct = 0; ct < 4; ++ct) {
            short8 b = *(const short8*)&Wb[ct * 16 + fl][kc + quad * 8];
            acc[ct] = __builtin_amdgcn_mfma_f32_16x16x32_bf16(a, b, acc[ct], 0, 0, 0);
        }
    }

    int rbase = r0 + wv * 16 + quad * 4;
#pragma unroll
    for (int r = 0; r < 4; ++r) {
        int row = rbase + r;
        if (row < N_NODES) {
            float di = dinv[row];
#pragma unroll
            for (int ct = 0; ct < 4; ++ct)
                Tb[(size_t)row * HID + ct * 16 + fl] = f2b(di * acc[ct][r]);
        }
    }
}

// ---------------- aggregation layer 1: Hb[i] = relu(dinv[i]*(Tb[i]+sum Tb[src])+b) ----------------

__global__ __launch_bounds__(256) void k_agg(const unsigned short* __restrict__ Tb,
                                             const int* __restrict__ rowptr,
                                             const int* __restrict__ deg,
                                             const float* __restrict__ dinv,
                                             const int* __restrict__ col,
                                             const float* __restrict__ bias,
                                             unsigned short* __restrict__ Hb) {
    int lane = threadIdx.x & 63;
    int node = blockIdx.x * 4 + (threadIdx.x >> 6);
    int grp = lane >> 3, fl = lane & 7;
    int e = __builtin_amdgcn_readfirstlane(rowptr[node]);
    int end = e + __builtin_amdgcn_readfirstlane(deg[node]) - 1;
    float a0 = 0.f, a1 = 0.f, a2 = 0.f, a3 = 0.f;
    float a4 = 0.f, a5 = 0.f, a6 = 0.f, a7 = 0.f;
    for (; e + 8 <= end; e += 8) {
        int s = col[e + grp];
        us8 tv = *(const us8*)(Tb + (size_t)s * HID + fl * 8);
        a0 += b2f(tv[0]); a1 += b2f(tv[1]); a2 += b2f(tv[2]); a3 += b2f(tv[3]);
        a4 += b2f(tv[4]); a5 += b2f(tv[5]); a6 += b2f(tv[6]); a7 += b2f(tv[7]);
    }
    if (e + grp < end) {
        int s = col[e + grp];
        us8 tv = *(const us8*)(Tb + (size_t)s * HID + fl * 8);
        a0 += b2f(tv[0]); a1 += b2f(tv[1]); a2 += b2f(tv[2]); a3 += b2f(tv[3]);
        a4 += b2f(tv[4]); a5 += b2f(tv[5]); a6 += b2f(tv[6]); a7 += b2f(tv[7]);
    }
    a0 += __shfl_xor(a0, 8);  a1 += __shfl_xor(a1, 8);
    a2 += __shfl_xor(a2, 8);  a3 += __shfl_xor(a3, 8);
    a4 += __shfl_xor(a4, 8);  a5 += __shfl_xor(a5, 8);
    a6 += __shfl_xor(a6, 8);  a7 += __shfl_xor(a7, 8);
    a0 += __shfl_xor(a0, 16); a1 += __shfl_xor(a1, 16);
    a2 += __shfl_xor(a2, 16); a3 += __shfl_xor(a3, 16);
    a4 += __shfl_xor(a4, 16); a5 += __shfl_xor(a5, 16);
    a6 += __shfl_xor(a6, 16); a7 += __shfl_xor(a7, 16);
    a0 += __shfl_xor(a0, 32); a1 += __shfl_xor(a1, 32);
    a2 += __shfl_xor(a2, 32); a3 += __shfl_xor(a3, 32);
    a4 += __shfl_xor(a4, 32); a5 += __shfl_xor(a5, 32);
    a6 += __shfl_xor(a6, 32); a7 += __shfl_xor(a7, 32);
    us8 sv = *(const us8*)(Tb + (size_t)node * HID + fl * 8);
    a0 += b2f(sv[0]); a1 += b2f(sv[1]); a2 += b2f(sv[2]); a3 += b2f(sv[3]);
    a4 += b2f(sv[4]); a5 += b2f(sv[5]); a6 += b2f(sv[6]); a7 += b2f(sv[7]);
    float di = dinv[node];
    float4 b0 = *(const float4*)(bias + fl * 8);
    float4 b1v = *(const float4*)(bias + fl * 8 + 4);
    a0 = fmaxf(fmaf(di, a0, b0.x), 0.f);
    a1 = fmaxf(fmaf(di, a1, b0.y), 0.f);
    a2 = fmaxf(fmaf(di, a2, b0.z), 0.f);
    a3 = fmaxf(fmaf(di, a3, b0.w), 0.f);
    a4 = fmaxf(fmaf(di, a4, b1v.x), 0.f);
    a5 = fmaxf(fmaf(di, a5, b1v.y), 0.f);
    a6 = fmaxf(fmaf(di, a6, b1v.z), 0.f);
    a7 = fmaxf(fmaf(di, a7, b1v.w), 0.f);
    if (grp == 0) {
        us8 o;
        o[0] = f2b(a0); o[1] = f2b(a1); o[2] = f2b(a2); o[3] = f2b(a3);
        o[4] = f2b(a4); o[5] = f2b(a5); o[6] = f2b(a6); o[7] = f2b(a7);
        *(us8*)(Hb + (size_t)node * HID + fl * 8) = o;
    }
}

// ---------------- aggregation layer 2 fused with layer-3 GEMV:
// h2 = relu(dinv*(Tb[i]+sum Tb[src])+b2);  z[i] = dinv[i] * dot(h2, w3l) ----------------

__global__ __launch_bounds__(256) void k_agg_z(const unsigned short* __restrict__ Tb,
                                               const int* __restrict__ rowptr,
                                               const int* __restrict__ deg,
                                               const float* __restrict__ dinv,
                                               const int* __restrict__ col,
                                               const float* __restrict__ bias,
                                               const float* __restrict__ w3l,
                                               float* __restrict__ z) {
    int lane = threadIdx.x & 63;
    int node = blockIdx.x * 4 + (threadIdx.x >> 6);
    int grp = lane >> 3, fl = lane & 7;
    int e = __builtin_amdgcn_readfirstlane(rowptr[node]);
    int end = e + __builtin_amdgcn_readfirstlane(deg[node]) - 1;
    float a0 = 0.f, a1 = 0.f, a2 = 0.f, a3 = 0.f;
    float a4 = 0.f, a5 = 0.f, a6 = 0.f, a7 = 0.f;
    for (; e + 8 <= end; e += 8) {
        int s = col[e + grp];
        us8 tv = *(const us8*)(Tb + (size_t)s * HID + fl * 8);
        a0 += b2f(tv[0]); a1 += b2f(tv[1]); a2 += b2f(tv[2]); a3 += b2f(tv[3]);
        a4 += b2f(tv[4]); a5 += b2f(tv[5]); a6 += b2f(tv[6]); a7 += b2f(tv[7]);
    }
    if (e + grp < end) {
        int s = col[e + grp];
        us8 tv = *(const us8*)(Tb + (size_t)s * HID + fl * 8);
        a0 += b2f(tv[0]); a1 += b2f(tv[1]); a2 += b2f(tv[2]); a3 += b2f(tv[3]);
        a4 += b2f(tv[4]); a5 += b2f(tv[5]); a6 += b2f(tv[6]); a7 += b2f(tv[7]);
    }
    a0 += __shfl_xor(a0, 8);  a1 += __shfl_xor(a1, 8);
    a2 += __shfl_xor(a2, 8);  a3 += __shfl_xor(a3, 8);
    a4 += __shfl_xor(a4, 8);  a5 += __shfl_xor(a5, 8);
    a6 += __shfl_xor(a6, 8);  a7 += __shfl_xor(a7, 8);
    a0 += __shfl_xor(a0, 16); a1 += __shfl_xor(a1, 16);
    a2 += __shfl_xor(a2, 16); a3 += __shfl_xor(a3, 16);
    a4 += __shfl_xor(a4, 16); a5 += __shfl_xor(a5, 16);
    a6 += __shfl_xor(a6, 16); a7 += __shfl_xor(a7, 16);
    a0 += __shfl_xor(a0, 32); a1 += __shfl_xor(a1, 32);
    a2 += __shfl_xor(a2, 32); a3 += __shfl_xor(a3, 32);
    a4 += __shfl_xor(a4, 32); a5 += __shfl_xor(a5, 32);
    a6 += __shfl_xor(a6, 32); a7 += __shfl_xor(a7, 32);
    us8 sv = *(const us8*)(Tb + (size_t)node * HID + fl * 8);
    a0 += b2f(sv[0]); a1 += b2f(sv[1]); a2 += b2f(sv[2]); a3 += b2f(sv[3]);
    a4 += b2f(sv[4]); a5 += b2f(sv[5]); a6 += b2f(sv[6]); a7 += b2f(sv[7]);
    float di = dinv[node];
    float4 b0 = *(const float4*)(bias + fl * 8);
    float4 b1v = *(const float4*)(bias + fl * 8 + 4);
    a0 = fmaxf(fmaf(di, a0, b0.x), 0.f);
    a1 = fmaxf(fmaf(di, a1, b0.y), 0.f);
    a2 = fmaxf(fmaf(di, a2, b0.z), 0.f);
    a3 = fmaxf(fmaf(di, a3, b0.w), 0.f);
    a4 = fmaxf(fmaf(di, a4, b1v.x), 0.f);
    a5 = fmaxf(fmaf(di, a5, b1v.y), 0.f);
    a6 = fmaxf(fmaf(di, a6, b1v.z), 0.f);
    a7 = fmaxf(fmaf(di, a7, b1v.w), 0.f);
    // fused layer-3 GEMV: every lane holds the full reduced row slice for its fl
    float4 w0 = *(const float4*)(w3l + fl * 8);
    float4 w1v = *(const float4*)(w3l + fl * 8 + 4);
    float s = a0 * w0.x + a1 * w0.y + a2 * w0.z + a3 * w0.w +
              a4 * w1v.x + a5 * w1v.y + a6 * w1v.z + a7 * w1v.w;
    s += __shfl_xor(s, 1);
    s += __shfl_xor(s, 2);
    s += __shfl_xor(s, 4);
    if (lane == 0) z[node] = di * s;
}

// scalar aggregation + pool: partial[g][blk] += b3wl + dinv[d]*(z[d] + sum z[src])
__global__ __launch_bounds__(256) void k_aggpool_s(const float* __restrict__ z,
                                                   const int* __restrict__ rowptr,
                                                   const int* __restrict__ deg,
                                                   const float* __restrict__ dinv,
                                                   const int* __restrict__ col,
                                                   const float* __restrict__ w3l,
                                                   const int* __restrict__ batch,
                                                   float* __restrict__ partial) {
    int i = blockIdx.x * 256 + threadIdx.x;
    if (i >= N_NODES) return;
    int e = rowptr[i];
    int end = e + deg[i] - 1;
    float s0 = z[i], s1 = 0.f, s2 = 0.f, s3 = 0.f;
    for (; e + 4 <= end; e += 4) {
        s0 += z[col[e]];
        s1 += z[col[e + 1]];
        s2 += z[col[e + 2]];
        s3 += z[col[e + 3]];
    }
    for (; e < end; ++e) s0 += z[col[e]];
    float s = w3l[HID] + dinv[i] * (s0 + s1 + s2 + s3);
    atomicAdd(&partial[batch[i] * 256 + (blockIdx.x & 255)], s);
}

__global__ void k_pool_reduce(const float* __restrict__ partial,
                              const float* __restrict__ bl,
                              float* __restrict__ out) {
    int g = blockIdx.x, t = threadIdx.x;
    float s = partial[g * 256 + t];
    s += __shfl_xor(s, 32);
    s += __shfl_xor(s, 16);
    s += __shfl_xor(s, 8);
    s += __shfl_xor(s, 4);
    s += __shfl_xor(s, 2);
    s += __shfl_xor(s, 1);
    __shared__ float ws[4];
    if ((t & 63) == 0) ws[t >> 6] = s;
    __syncthreads();
    if (t == 0) out[g] = bl[0] + ws[0] + ws[1] + ws[2] + ws[3];
}

extern "C" void kernel_launch(void* const* d_in, const int* in_sizes, int n_in,
                              void* d_out, int out_size, void* d_ws, size_t ws_size,
                              hipStream_t stream) {
    const float* x     = (const float*)d_in[0];
    const int*   ei    = (const int*)d_in[1];
    const int*   batch = (const int*)d_in[2];
    const float* W1    = (const float*)d_in[3];
    const float* b1    = (const float*)d_in[4];
    const float* W2    = (const float*)d_in[5];
    const float* b2    = (const float*)d_in[6];
    const float* W3    = (const float*)d_in[7];
    const float* b3    = (const float*)d_in[8];
    const float* Wl    = (const float*)d_in[9];
    const float* bl    = (const float*)d_in[10];
    float* out = (float*)d_out;

    char* p = (char*)d_ws;
    unsigned short* tb = (unsigned short*)p; p += (size_t)N_NODES * HID * 2;  // 12.8 MB
    unsigned short* hB = (unsigned short*)p; p += (size_t)N_NODES * HID * 2;  // 12.8 MB
    int*   col     = (int*)p;   p += (size_t)(N_EDGES + 16) * 4;              // 6.4 MB
    int*   ebuck   = (int*)p;   p += (size_t)N_EDGES * 4;                     // 6.4 MB
    int*   deg     = (int*)p;   p += (size_t)N_NODES * 4;
    float* dinv    = (float*)p; p += (size_t)N_NODES * 4;
    int*   rowptr  = (int*)p;   p += (size_t)N_NODES * 4;
    float* z       = (float*)p; p += (size_t)N_NODES * 4;
    int*   bcount  = (int*)p;   p += (NBUCK + 1) * 4;
    int*   bfillr  = (int*)p;   p += (NBUCK + 1) * 4;
    int*   bsum    = (int*)p;   p += 512 * 4;
    int*   bar     = (int*)p;   p += 16 * 4;
    float* partial = (float*)p; p += (size_t)N_GRAPHS * 256 * 4;
    unsigned short* wt1 = (unsigned short*)p; p += (size_t)IN_DIM * HID * 2;
    unsigned short* wt2 = (unsigned short*)p; p += (size_t)HID * HID * 2;
    float* w3l     = (float*)p; p += 128 * 4;   // w3l[64] + b3wl at [64]

    const int* src  = ei;
    const int* dstp = ei + N_EDGES;

    const int nb = (N_NODES + 255) / 256;            // 391
    const int gemm_blocks = (N_NODES + 63) / 64;     // 1563
    const int node_wave_blocks = (N_NODES + 3) / 4;  // 25000

    k_prep<<<128, 256, 0, stream>>>(W1, W2, W3, Wl, b3, wt1, wt2, w3l,
                                    bcount, bfillr, partial, bar);
    k_setup<<<NBUCK, 256, 0, stream>>>(src, dstp, bcount, bfillr, ebuck,
                                       deg, dinv, bsum, rowptr, col, bar);

    k_gemm1<<<gemm_blocks, 256, 0, stream>>>(x, wt1, dinv, tb);
    k_agg<<<node_wave_blocks, 256, 0, stream>>>(tb, rowptr, deg, dinv, col, b1, hB);
    k_gemm2<<<gemm_blocks, 256, 0, stream>>>(hB, wt2, dinv, tb);
    k_agg_z<<<node_wave_blocks, 256, 0, stream>>>(tb, rowptr, deg, dinv, col, b2, w3l, z);

    k_aggpool_s<<<nb, 256, 0, stream>>>(z, rowptr, deg, dinv, col, w3l, batch, partial);
    k_pool_reduce<<<N_GRAPHS, 256, 0, stream>>>(partial, bl, out);
}

// Round 2
// 385.834 us; speedup vs baseline: 1.2970x; 1.2970x over previous
//
#include <hip/hip_runtime.h>

#define N_NODES 100000
#define N_EDGES 1600000
#define IN_DIM 256
#define HID 64
#define N_GRAPHS 100
#define BSHIFT 8
#define NBUCK 391   // ceil(N_NODES / 256) == ceil(N_EDGES / CHUNK)
#define CHUNK 4096  // edges per block in bucket passes

typedef __attribute__((ext_vector_type(8))) short short8;
typedef __attribute__((ext_vector_type(8))) unsigned short us8;
typedef __attribute__((ext_vector_type(4))) float floatx4;

// bf16 helpers (RNE)
__device__ __forceinline__ unsigned short f2b(float f) {
    unsigned int u = __float_as_uint(f);
    unsigned int r = (u + 0x7FFFu + ((u >> 16) & 1u)) >> 16;
    return (unsigned short)r;
}
__device__ __forceinline__ float b2f(unsigned short b) {
    return __uint_as_float(((unsigned int)b) << 16);
}

// inclusive scan of 512 ints, sA = input, sB = ping-pong; returns result ptr.
// caller must __syncthreads() after filling sA.
__device__ __forceinline__ int* scan512(int* sA, int* sB, int t) {
    int* A = sA;
    int* B = sB;
    for (int off = 1; off < 512; off <<= 1) {
        B[t] = A[t] + ((t >= off) ? A[t - off] : 0);
        B[t + 256] = A[t + 256] + A[t + 256 - off];
        __syncthreads();
        int* tmp = A; A = B; B = tmp;
    }
    return A;
}

// ---------------- prep: W transpose/bf16, w3l = W3@Wl, zero counters ----------------

__global__ void k_prep(const float* __restrict__ W1, const float* __restrict__ W2,
                       const float* __restrict__ W3, const float* __restrict__ Wl,
                       const float* __restrict__ b3,
                       unsigned short* __restrict__ wt1, unsigned short* __restrict__ wt2,
                       float* __restrict__ w3l,
                       int* __restrict__ bcount, int* __restrict__ bfillrel,
                       float* __restrict__ partial) {
    int i = blockIdx.x * 256 + threadIdx.x;
    if (i < IN_DIM * HID) {
        int k = i >> 6, n = i & 63;
        wt1[n * IN_DIM + k] = f2b(W1[i]);
    }
    if (i < HID * HID) {
        int k = i >> 6, n = i & 63;
        wt2[n * HID + k] = f2b(W2[i]);
    }
    if (i < NBUCK) { bcount[i] = 0; bfillrel[i] = 0; }
    if (i < N_GRAPHS * 256) partial[i] = 0.f;
    if (blockIdx.x == 0) {
        int t = threadIdx.x;
        if (t < HID) {
            float s = 0.f;
            for (int n = 0; n < HID; ++n) s += W3[t * HID + n] * Wl[n];
            w3l[t] = s;
        } else if (t == HID) {
            float s = 0.f;
            for (int n = 0; n < HID; ++n) s += b3[n] * Wl[n];
            w3l[HID] = s;  // b3wl
        }
    }
}

// ---------------- bucketed edge partition ----------------

__global__ __launch_bounds__(256) void k_bhist(const int* __restrict__ dst,
                                               int* __restrict__ bcount) {
    __shared__ int lc[NBUCK];
    int t = threadIdx.x;
    for (int b = t; b < NBUCK; b += 256) lc[b] = 0;
    __syncthreads();
    int base = blockIdx.x * CHUNK;
#pragma unroll
    for (int i = 0; i < 16; ++i) {
        int e = base + i * 256 + t;
        if (e < N_EDGES) atomicAdd(&lc[dst[e] >> BSHIFT], 1);
    }
    __syncthreads();
    for (int b = t; b < NBUCK; b += 256)
        if (lc[b]) atomicAdd(&bcount[b], lc[b]);
}

// scatter edges into buckets; each block redundantly scans bcount -> bucket starts
// (replaces the separate 1-block k_bscan). Block 0 publishes bstart for later kernels.
__global__ __launch_bounds__(256) void k_bscatter(const int* __restrict__ src,
                                                  const int* __restrict__ dst,
                                                  const int* __restrict__ bcount,
                                                  int* __restrict__ bfillrel,
                                                  int* __restrict__ ebuck,
                                                  int* __restrict__ bstart) {
    __shared__ int lc[NBUCK];
    __shared__ int ebst[NBUCK];
    __shared__ int sA[512];
    __shared__ int sB[512];
    const int b = blockIdx.x, t = threadIdx.x;

    for (int i = t; i < NBUCK; i += 256) lc[i] = 0;
    __syncthreads();
    const int base = b * CHUNK;
    int pk[16], bk[16], rk[16];
#pragma unroll
    for (int i = 0; i < 16; ++i) {
        int e = base + i * 256 + t;
        rk[i] = -1;
        if (e < N_EDGES) {
            int s = src[e], d = dst[e];
            bk[i] = d >> BSHIFT;
            pk[i] = (s << BSHIFT) | (d & 255);
            rk[i] = atomicAdd(&lc[bk[i]], 1);
        }
    }

    // per-block exclusive scan of bcount (complete: kernel boundary after k_bhist)
    int v0 = (t < NBUCK) ? bcount[t] : 0;
    int v1 = (t + 256 < NBUCK) ? bcount[t + 256] : 0;
    sA[t] = v0;
    sA[t + 256] = v1;
    __syncthreads();
    int* A = scan512(sA, sB, t);
    if (t < NBUCK) ebst[t] = A[t] - v0;
    if (t + 256 < NBUCK) ebst[t + 256] = A[t + 256] - v1;
    __syncthreads();

    if (b == 0) {
        for (int i = t; i < NBUCK; i += 256) bstart[i] = ebst[i];
        if (t == 0) bstart[NBUCK] = N_EDGES;
    }

    // claim global slots per bucket, then scatter
    for (int i = t; i < NBUCK; i += 256)
        lc[i] = lc[i] ? (ebst[i] + atomicAdd(&bfillrel[i], lc[i])) : 0;
    __syncthreads();
#pragma unroll
    for (int i = 0; i < 16; ++i)
        if (rk[i] >= 0) ebuck[lc[bk[i]] + rk[i]] = pk[i];
}

// per-bucket degree histogram + dinv + bucket-sum of (deg-1) for rowptr scan
__global__ __launch_bounds__(256) void k_degscan(const int* __restrict__ bstart,
                                                 const int* __restrict__ ebuck,
                                                 int* __restrict__ deg,
                                                 float* __restrict__ dinv,
                                                 int* __restrict__ bsum) {
    __shared__ int ld[256];
    __shared__ int rs[256];
    int b = blockIdx.x, t = threadIdx.x;
    ld[t] = 1;  // self loop
    __syncthreads();
    int s = bstart[b], e = bstart[b + 1];
    for (int j = s + t; j < e; j += 256) atomicAdd(&ld[ebuck[j] & 255], 1);
    __syncthreads();
    int node = (b << BSHIFT) + t;
    int d = ld[t];
    if (node < N_NODES) {
        deg[node] = d;
        dinv[node] = rsqrtf((float)d);
    }
    rs[t] = (node < N_NODES) ? d - 1 : 0;
    __syncthreads();
    for (int off = 128; off; off >>= 1) {
        if (t < off) rs[t] += rs[t + off];
        __syncthreads();
    }
    if (t == 0) bsum[b] = rs[0];
}

// rowptr + CSR fill; each block redundantly scans bsum for its global bucket offset
// (replaces the separate 1-block k_scan2)
__global__ __launch_bounds__(256) void k_fill2(const int* __restrict__ bstart,
                                               const int* __restrict__ ebuck,
                                               const int* __restrict__ deg,
                                               const int* __restrict__ bsum,
                                               int* __restrict__ rowptr,
                                               int* __restrict__ col) {
    __shared__ int sA[512];
    __shared__ int sB[512];
    __shared__ int lf[256];
    const int b = blockIdx.x, t = threadIdx.x;

    // global bucket offset: exclusive scan of bsum up to b
    sA[t] = (t < NBUCK) ? bsum[t] : 0;
    sA[t + 256] = (t + 256 < NBUCK) ? bsum[t + 256] : 0;
    __syncthreads();
    int* A = scan512(sA, sB, t);
    const int off_b = (b > 0) ? A[b - 1] : 0;
    __syncthreads();

    // in-bucket exclusive scan of (deg-1) over 256 nodes
    const int node = (b << BSHIFT) + t;
    const int c = (node < N_NODES) ? deg[node] - 1 : 0;
    sA[t] = c;
    __syncthreads();
    for (int off = 1; off < 256; off <<= 1) {
        int u = 0;
        if (t >= off) u = sA[t - off];
        __syncthreads();
        sA[t] += u;
        __syncthreads();
    }
    const int pos = off_b + sA[t] - c;  // exclusive
    if (node < N_NODES) rowptr[node] = pos;
    lf[t] = pos;
    __syncthreads();
    const int bs = bstart[b], be = bstart[b + 1];
    for (int j = bs + t; j < be; j += 256) {
        int v = ebuck[j];
        int p = atomicAdd(&lf[v & 255], 1);
        col[p] = v >> BSHIFT;
    }
}

// ---------------- MFMA GEMM1: Tb = dinv * (X[fp32] @ W1) ----------------

__global__ __launch_bounds__(256) void k_gemm1(const float* __restrict__ X,
                                               const unsigned short* __restrict__ Wt,
                                               const float* __restrict__ dinv,
                                               unsigned short* __restrict__ Tb) {
    __shared__ unsigned short Wb[64][264];
    const int t = threadIdx.x;
    const int lane = t & 63, wv = t >> 6;
    const int fl = lane & 15, quad = lane >> 4;
    const int r0 = blockIdx.x * 64;

    for (int g = t; g < 64 * 32; g += 256) {
        int n = g >> 5, kc8 = g & 31;
        *(us8*)&Wb[n][kc8 * 8] = *(const us8*)(Wt + n * IN_DIM + kc8 * 8);
    }

    const int arow = r0 + wv * 16 + fl;
    const bool valid = arow < N_NODES;
    const float* xp = X + (size_t)(valid ? arow : 0) * IN_DIM;

    floatx4 acc[4];
#pragma unroll
    for (int j = 0; j < 4; ++j) acc[j] = (floatx4){0.f, 0.f, 0.f, 0.f};

    __syncthreads();

#pragma unroll
    for (int kc = 0; kc < IN_DIM; kc += 32) {
        float4 x0 = make_float4(0.f, 0.f, 0.f, 0.f);
        float4 x1 = make_float4(0.f, 0.f, 0.f, 0.f);
        if (valid) {
            x0 = *(const float4*)(xp + kc + quad * 8);
            x1 = *(const float4*)(xp + kc + quad * 8 + 4);
        }
        short8 a;
        a[0] = (short)f2b(x0.x); a[1] = (short)f2b(x0.y);
        a[2] = (short)f2b(x0.z); a[3] = (short)f2b(x0.w);
        a[4] = (short)f2b(x1.x); a[5] = (short)f2b(x1.y);
        a[6] = (short)f2b(x1.z); a[7] = (short)f2b(x1.w);
#pragma unroll
        for (int ct = 0; ct < 4; ++ct) {
            short8 b = *(const short8*)&Wb[ct * 16 + fl][kc + quad * 8];
            acc[ct] = __builtin_amdgcn_mfma_f32_16x16x32_bf16(a, b, acc[ct], 0, 0, 0);
        }
    }

    int rbase = r0 + wv * 16 + quad * 4;
#pragma unroll
    for (int r = 0; r < 4; ++r) {
        int row = rbase + r;
        if (row < N_NODES) {
            float di = dinv[row];
#pragma unroll
            for (int ct = 0; ct < 4; ++ct)
                Tb[(size_t)row * HID + ct * 16 + fl] = f2b(di * acc[ct][r]);
        }
    }
}

// ---------------- MFMA GEMM2: Tb = dinv * (Hb[bf16] @ W) ----------------

__global__ __launch_bounds__(256) void k_gemm2(const unsigned short* __restrict__ Xin,
                                               const unsigned short* __restrict__ Wt,
                                               const float* __restrict__ dinv,
                                               unsigned short* __restrict__ Tb) {
    __shared__ unsigned short Wb[64][72];
    const int t = threadIdx.x;
    const int lane = t & 63, wv = t >> 6;
    const int fl = lane & 15, quad = lane >> 4;
    const int r0 = blockIdx.x * 64;

    for (int g = t; g < 64 * 8; g += 256) {
        int n = g >> 3, kc8 = g & 7;
        *(us8*)&Wb[n][kc8 * 8] = *(const us8*)(Wt + n * HID + kc8 * 8);
    }

    const int arow = r0 + wv * 16 + fl;
    const bool valid = arow < N_NODES;
    const unsigned short* xp = Xin + (size_t)(valid ? arow : 0) * HID;

    floatx4 acc[4];
#pragma unroll
    for (int j = 0; j < 4; ++j) acc[j] = (floatx4){0.f, 0.f, 0.f, 0.f};

    __syncthreads();

#pragma unroll
    for (int kc = 0; kc < HID; kc += 32) {
        short8 a = (short8){0, 0, 0, 0, 0, 0, 0, 0};
        if (valid) a = *(const short8*)(xp + kc + quad * 8);
#pragma unroll
        for (int ct = 0; ct < 4; ++ct) {
            short8 b = *(const short8*)&Wb[ct * 16 + fl][kc + quad * 8];
            acc[ct] = __builtin_amdgcn_mfma_f32_16x16x32_bf16(a, b, acc[ct], 0, 0, 0);
        }
    }

    int rbase = r0 + wv * 16 + quad * 4;
#pragma unroll
    for (int r = 0; r < 4; ++r) {
        int row = rbase + r;
        if (row < N_NODES) {
            float di = dinv[row];
#pragma unroll
            for (int ct = 0; ct < 4; ++ct)
                Tb[(size_t)row * HID + ct * 16 + fl] = f2b(di * acc[ct][r]);
        }
    }
}

// ---------------- aggregation layer 1: Hb[i] = relu(dinv[i]*(Tb[i]+sum Tb[src])+b) ----------------

__global__ __launch_bounds__(256) void k_agg(const unsigned short* __restrict__ Tb,
                                             const int* __restrict__ rowptr,
                                             const int* __restrict__ deg,
                                             const float* __restrict__ dinv,
                                             const int* __restrict__ col,
                                             const float* __restrict__ bias,
                                             unsigned short* __restrict__ Hb) {
    int lane = threadIdx.x & 63;
    int node = blockIdx.x * 4 + (threadIdx.x >> 6);
    int grp = lane >> 3, fl = lane & 7;
    int e = __builtin_amdgcn_readfirstlane(rowptr[node]);
    int end = e + __builtin_amdgcn_readfirstlane(deg[node]) - 1;
    float a0 = 0.f, a1 = 0.f, a2 = 0.f, a3 = 0.f;
    float a4 = 0.f, a5 = 0.f, a6 = 0.f, a7 = 0.f;
    for (; e + 8 <= end; e += 8) {
        int s = col[e + grp];
        us8 tv = *(const us8*)(Tb + (size_t)s * HID + fl * 8);
        a0 += b2f(tv[0]); a1 += b2f(tv[1]); a2 += b2f(tv[2]); a3 += b2f(tv[3]);
        a4 += b2f(tv[4]); a5 += b2f(tv[5]); a6 += b2f(tv[6]); a7 += b2f(tv[7]);
    }
    if (e + grp < end) {
        int s = col[e + grp];
        us8 tv = *(const us8*)(Tb + (size_t)s * HID + fl * 8);
        a0 += b2f(tv[0]); a1 += b2f(tv[1]); a2 += b2f(tv[2]); a3 += b2f(tv[3]);
        a4 += b2f(tv[4]); a5 += b2f(tv[5]); a6 += b2f(tv[6]); a7 += b2f(tv[7]);
    }
    a0 += __shfl_xor(a0, 8);  a1 += __shfl_xor(a1, 8);
    a2 += __shfl_xor(a2, 8);  a3 += __shfl_xor(a3, 8);
    a4 += __shfl_xor(a4, 8);  a5 += __shfl_xor(a5, 8);
    a6 += __shfl_xor(a6, 8);  a7 += __shfl_xor(a7, 8);
    a0 += __shfl_xor(a0, 16); a1 += __shfl_xor(a1, 16);
    a2 += __shfl_xor(a2, 16); a3 += __shfl_xor(a3, 16);
    a4 += __shfl_xor(a4, 16); a5 += __shfl_xor(a5, 16);
    a6 += __shfl_xor(a6, 16); a7 += __shfl_xor(a7, 16);
    a0 += __shfl_xor(a0, 32); a1 += __shfl_xor(a1, 32);
    a2 += __shfl_xor(a2, 32); a3 += __shfl_xor(a3, 32);
    a4 += __shfl_xor(a4, 32); a5 += __shfl_xor(a5, 32);
    a6 += __shfl_xor(a6, 32); a7 += __shfl_xor(a7, 32);
    us8 sv = *(const us8*)(Tb + (size_t)node * HID + fl * 8);
    a0 += b2f(sv[0]); a1 += b2f(sv[1]); a2 += b2f(sv[2]); a3 += b2f(sv[3]);
    a4 += b2f(sv[4]); a5 += b2f(sv[5]); a6 += b2f(sv[6]); a7 += b2f(sv[7]);
    float di = dinv[node];
    float4 b0 = *(const float4*)(bias + fl * 8);
    float4 b1v = *(const float4*)(bias + fl * 8 + 4);
    a0 = fmaxf(fmaf(di, a0, b0.x), 0.f);
    a1 = fmaxf(fmaf(di, a1, b0.y), 0.f);
    a2 = fmaxf(fmaf(di, a2, b0.z), 0.f);
    a3 = fmaxf(fmaf(di, a3, b0.w), 0.f);
    a4 = fmaxf(fmaf(di, a4, b1v.x), 0.f);
    a5 = fmaxf(fmaf(di, a5, b1v.y), 0.f);
    a6 = fmaxf(fmaf(di, a6, b1v.z), 0.f);
    a7 = fmaxf(fmaf(di, a7, b1v.w), 0.f);
    if (grp == 0) {
        us8 o;
        o[0] = f2b(a0); o[1] = f2b(a1); o[2] = f2b(a2); o[3] = f2b(a3);
        o[4] = f2b(a4); o[5] = f2b(a5); o[6] = f2b(a6); o[7] = f2b(a7);
        *(us8*)(Hb + (size_t)node * HID + fl * 8) = o;
    }
}

// ---------------- aggregation layer 2 fused with layer-3 GEMV:
// h2 = relu(dinv*(Tb[i]+sum Tb[src])+b2);  z[i] = dinv[i] * dot(h2, w3l) ----------------

__global__ __launch_bounds__(256) void k_agg_z(const unsigned short* __restrict__ Tb,
                                               const int* __restrict__ rowptr,
                                               const int* __restrict__ deg,
                                               const float* __restrict__ dinv,
                                               const int* __restrict__ col,
                                               const float* __restrict__ bias,
                                               const float* __restrict__ w3l,
                                               float* __restrict__ z) {
    int lane = threadIdx.x & 63;
    int node = blockIdx.x * 4 + (threadIdx.x >> 6);
    int grp = lane >> 3, fl = lane & 7;
    int e = __builtin_amdgcn_readfirstlane(rowptr[node]);
    int end = e + __builtin_amdgcn_readfirstlane(deg[node]) - 1;
    float a0 = 0.f, a1 = 0.f, a2 = 0.f, a3 = 0.f;
    float a4 = 0.f, a5 = 0.f, a6 = 0.f, a7 = 0.f;
    for (; e + 8 <= end; e += 8) {
        int s = col[e + grp];
        us8 tv = *(const us8*)(Tb + (size_t)s * HID + fl * 8);
        a0 += b2f(tv[0]); a1 += b2f(tv[1]); a2 += b2f(tv[2]); a3 += b2f(tv[3]);
        a4 += b2f(tv[4]); a5 += b2f(tv[5]); a6 += b2f(tv[6]); a7 += b2f(tv[7]);
    }
    if (e + grp < end) {
        int s = col[e + grp];
        us8 tv = *(const us8*)(Tb + (size_t)s * HID + fl * 8);
        a0 += b2f(tv[0]); a1 += b2f(tv[1]); a2 += b2f(tv[2]); a3 += b2f(tv[3]);
        a4 += b2f(tv[4]); a5 += b2f(tv[5]); a6 += b2f(tv[6]); a7 += b2f(tv[7]);
    }
    a0 += __shfl_xor(a0, 8);  a1 += __shfl_xor(a1, 8);
    a2 += __shfl_xor(a2, 8);  a3 += __shfl_xor(a3, 8);
    a4 += __shfl_xor(a4, 8);  a5 += __shfl_xor(a5, 8);
    a6 += __shfl_xor(a6, 8);  a7 += __shfl_xor(a7, 8);
    a0 += __shfl_xor(a0, 16); a1 += __shfl_xor(a1, 16);
    a2 += __shfl_xor(a2, 16); a3 += __shfl_xor(a3, 16);
    a4 += __shfl_xor(a4, 16); a5 += __shfl_xor(a5, 16);
    a6 += __shfl_xor(a6, 16); a7 += __shfl_xor(a7, 16);
    a0 += __shfl_xor(a0, 32); a1 += __shfl_xor(a1, 32);
    a2 += __shfl_xor(a2, 32); a3 += __shfl_xor(a3, 32);
    a4 += __shfl_xor(a4, 32); a5 += __shfl_xor(a5, 32);
    a6 += __shfl_xor(a6, 32); a7 += __shfl_xor(a7, 32);
    us8 sv = *(const us8*)(Tb + (size_t)node * HID + fl * 8);
    a0 += b2f(sv[0]); a1 += b2f(sv[1]); a2 += b2f(sv[2]); a3 += b2f(sv[3]);
    a4 += b2f(sv[4]); a5 += b2f(sv[5]); a6 += b2f(sv[6]); a7 += b2f(sv[7]);
    float di = dinv[node];
    float4 b0 = *(const float4*)(bias + fl * 8);
    float4 b1v = *(const float4*)(bias + fl * 8 + 4);
    a0 = fmaxf(fmaf(di, a0, b0.x), 0.f);
    a1 = fmaxf(fmaf(di, a1, b0.y), 0.f);
    a2 = fmaxf(fmaf(di, a2, b0.z), 0.f);
    a3 = fmaxf(fmaf(di, a3, b0.w), 0.f);
    a4 = fmaxf(fmaf(di, a4, b1v.x), 0.f);
    a5 = fmaxf(fmaf(di, a5, b1v.y), 0.f);
    a6 = fmaxf(fmaf(di, a6, b1v.z), 0.f);
    a7 = fmaxf(fmaf(di, a7, b1v.w), 0.f);
    // fused layer-3 GEMV: lanes of each 8-group jointly hold the full reduced row
    float4 w0 = *(const float4*)(w3l + fl * 8);
    float4 w1v = *(const float4*)(w3l + fl * 8 + 4);
    float s = a0 * w0.x + a1 * w0.y + a2 * w0.z + a3 * w0.w +
              a4 * w1v.x + a5 * w1v.y + a6 * w1v.z + a7 * w1v.w;
    s += __shfl_xor(s, 1);
    s += __shfl_xor(s, 2);
    s += __shfl_xor(s, 4);
    if (lane == 0) z[node] = di * s;
}

// scalar aggregation + pool: partial[g][blk] += b3wl + dinv[d]*(z[d] + sum z[src])
__global__ __launch_bounds__(256) void k_aggpool_s(const float* __restrict__ z,
                                                   const int* __restrict__ rowptr,
                                                   const int* __restrict__ deg,
                                                   const float* __restrict__ dinv,
                                                   const int* __restrict__ col,
                                                   const float* __restrict__ w3l,
                                                   const int* __restrict__ batch,
                                                   float* __restrict__ partial) {
    int i = blockIdx.x * 256 + threadIdx.x;
    if (i >= N_NODES) return;
    int e = rowptr[i];
    int end = e + deg[i] - 1;
    float s0 = z[i], s1 = 0.f, s2 = 0.f, s3 = 0.f;
    for (; e + 4 <= end; e += 4) {
        s0 += z[col[e]];
        s1 += z[col[e + 1]];
        s2 += z[col[e + 2]];
        s3 += z[col[e + 3]];
    }
    for (; e < end; ++e) s0 += z[col[e]];
    float s = w3l[HID] + dinv[i] * (s0 + s1 + s2 + s3);
    atomicAdd(&partial[batch[i] * 256 + (blockIdx.x & 255)], s);
}

__global__ void k_pool_reduce(const float* __restrict__ partial,
                              const float* __restrict__ bl,
                              float* __restrict__ out) {
    int g = blockIdx.x, t = threadIdx.x;
    float s = partial[g * 256 + t];
    s += __shfl_xor(s, 32);
    s += __shfl_xor(s, 16);
    s += __shfl_xor(s, 8);
    s += __shfl_xor(s, 4);
    s += __shfl_xor(s, 2);
    s += __shfl_xor(s, 1);
    __shared__ float ws[4];
    if ((t & 63) == 0) ws[t >> 6] = s;
    __syncthreads();
    if (t == 0) out[g] = bl[0] + ws[0] + ws[1] + ws[2] + ws[3];
}

extern "C" void kernel_launch(void* const* d_in, const int* in_sizes, int n_in,
                              void* d_out, int out_size, void* d_ws, size_t ws_size,
                              hipStream_t stream) {
    const float* x     = (const float*)d_in[0];
    const int*   ei    = (const int*)d_in[1];
    const int*   batch = (const int*)d_in[2];
    const float* W1    = (const float*)d_in[3];
    const float* b1    = (const float*)d_in[4];
    const float* W2    = (const float*)d_in[5];
    const float* b2    = (const float*)d_in[6];
    const float* W3    = (const float*)d_in[7];
    const float* b3    = (const float*)d_in[8];
    const float* Wl    = (const float*)d_in[9];
    const float* bl    = (const float*)d_in[10];
    float* out = (float*)d_out;

    char* p = (char*)d_ws;
    unsigned short* tb = (unsigned short*)p; p += (size_t)N_NODES * HID * 2;  // 12.8 MB
    unsigned short* hB = (unsigned short*)p; p += (size_t)N_NODES * HID * 2;  // 12.8 MB
    int*   col     = (int*)p;   p += (size_t)(N_EDGES + 16) * 4;              // 6.4 MB
    int*   ebuck   = (int*)p;   p += (size_t)N_EDGES * 4;                     // 6.4 MB
    int*   deg     = (int*)p;   p += (size_t)N_NODES * 4;
    float* dinv    = (float*)p; p += (size_t)N_NODES * 4;
    int*   rowptr  = (int*)p;   p += (size_t)N_NODES * 4;
    float* z       = (float*)p; p += (size_t)N_NODES * 4;
    int*   bcount  = (int*)p;   p += (NBUCK + 1) * 4;
    int*   bstart  = (int*)p;   p += (NBUCK + 1) * 4;
    int*   bfillr  = (int*)p;   p += (NBUCK + 1) * 4;
    int*   bsum    = (int*)p;   p += 512 * 4;
    float* partial = (float*)p; p += (size_t)N_GRAPHS * 256 * 4;
    unsigned short* wt1 = (unsigned short*)p; p += (size_t)IN_DIM * HID * 2;
    unsigned short* wt2 = (unsigned short*)p; p += (size_t)HID * HID * 2;
    float* w3l     = (float*)p; p += 128 * 4;   // w3l[64] + b3wl at [64]

    const int* src  = ei;
    const int* dstp = ei + N_EDGES;

    const int nb = (N_NODES + 255) / 256;            // 391
    const int cb = (N_EDGES + CHUNK - 1) / CHUNK;    // 391
    const int gemm_blocks = (N_NODES + 63) / 64;     // 1563
    const int node_wave_blocks = (N_NODES + 3) / 4;  // 25000

    k_prep<<<128, 256, 0, stream>>>(W1, W2, W3, Wl, b3, wt1, wt2, w3l,
                                    bcount, bfillr, partial);
    k_bhist<<<cb, 256, 0, stream>>>(dstp, bcount);
    k_bscatter<<<cb, 256, 0, stream>>>(src, dstp, bcount, bfillr, ebuck, bstart);
    k_degscan<<<NBUCK, 256, 0, stream>>>(bstart, ebuck, deg, dinv, bsum);
    k_fill2<<<NBUCK, 256, 0, stream>>>(bstart, ebuck, deg, bsum, rowptr, col);

    k_gemm1<<<gemm_blocks, 256, 0, stream>>>(x, wt1, dinv, tb);
    k_agg<<<node_wave_blocks, 256, 0, stream>>>(tb, rowptr, deg, dinv, col, b1, hB);
    k_gemm2<<<gemm_blocks, 256, 0, stream>>>(hB, wt2, dinv, tb);
    k_agg_z<<<node_wave_blocks, 256, 0, stream>>>(tb, rowptr, deg, dinv, col, b2, w3l, z);

    k_aggpool_s<<<nb, 256, 0, stream>>>(z, rowptr, deg, dinv, col, w3l, batch, partial);
    k_pool_reduce<<<N_GRAPHS, 256, 0, stream>>>(partial, bl, out);
}

// Round 3
// 365.632 us; speedup vs baseline: 1.3687x; 1.0553x over previous
//
#include <hip/hip_runtime.h>

#define N_NODES 100000
#define N_EDGES 1600000
#define IN_DIM 256
#define HID 64
#define N_GRAPHS 100
#define BSHIFT 8
#define NBUCK 391   // ceil(N_NODES / 256) == ceil(N_EDGES / CHUNK)
#define CHUNK 4096  // edges per block in scatter pass
#define BCAP 5120   // fixed bucket capacity (mean 4096, sigma ~64 -> 16 sigma headroom)

typedef __attribute__((ext_vector_type(8))) short short8;
typedef __attribute__((ext_vector_type(8))) unsigned short us8;
typedef __attribute__((ext_vector_type(4))) float floatx4;

// bf16 helpers (RNE)
__device__ __forceinline__ unsigned short f2b(float f) {
    unsigned int u = __float_as_uint(f);
    unsigned int r = (u + 0x7FFFu + ((u >> 16) & 1u)) >> 16;
    return (unsigned short)r;
}
__device__ __forceinline__ float b2f(unsigned short b) {
    return __uint_as_float(((unsigned int)b) << 16);
}

// ---------------- prep: W transpose/bf16, w3l = W3@Wl, zero counters ----------------

__global__ void k_prep(const float* __restrict__ W1, const float* __restrict__ W2,
                       const float* __restrict__ W3, const float* __restrict__ Wl,
                       const float* __restrict__ b3,
                       unsigned short* __restrict__ wt1, unsigned short* __restrict__ wt2,
                       float* __restrict__ w3l,
                       int* __restrict__ bcnt, float* __restrict__ partial) {
    int i = blockIdx.x * 256 + threadIdx.x;
    if (i < IN_DIM * HID) {
        int k = i >> 6, n = i & 63;
        wt1[n * IN_DIM + k] = f2b(W1[i]);
    }
    if (i < HID * HID) {
        int k = i >> 6, n = i & 63;
        wt2[n * HID + k] = f2b(W2[i]);
    }
    if (i < NBUCK) bcnt[i] = 0;
    if (i < N_GRAPHS * 256) partial[i] = 0.f;
    if (blockIdx.x == 0) {
        int t = threadIdx.x;
        if (t < HID) {
            float s = 0.f;
            for (int n = 0; n < HID; ++n) s += W3[t * HID + n] * Wl[n];
            w3l[t] = s;
        } else if (t == HID) {
            float s = 0.f;
            for (int n = 0; n < HID; ++n) s += b3[n] * Wl[n];
            w3l[HID] = s;  // b3wl
        }
    }
}

// ---------------- one-pass bucket scatter (fixed-capacity buckets) ----------------

__global__ __launch_bounds__(256) void k_scatter(const int* __restrict__ src,
                                                 const int* __restrict__ dst,
                                                 int* __restrict__ bcnt,
                                                 int* __restrict__ ebuckF) {
    __shared__ int lc[NBUCK];
    const int b = blockIdx.x, t = threadIdx.x;
    for (int i = t; i < NBUCK; i += 256) lc[i] = 0;
    __syncthreads();
    const int base = b * CHUNK;
    int pk[16], bk[16], rk[16];
#pragma unroll
    for (int i = 0; i < 16; ++i) {
        int e = base + i * 256 + t;
        rk[i] = -1;
        if (e < N_EDGES) {
            int s = src[e], d = dst[e];
            bk[i] = d >> BSHIFT;
            pk[i] = (s << BSHIFT) | (d & 255);
            rk[i] = atomicAdd(&lc[bk[i]], 1);
        }
    }
    __syncthreads();
    // claim a base slot range per non-empty bucket directly on the global counter
    for (int i = t; i < NBUCK; i += 256)
        lc[i] = lc[i] ? atomicAdd(&bcnt[i], lc[i]) : 0;
    __syncthreads();
#pragma unroll
    for (int i = 0; i < 16; ++i)
        if (rk[i] >= 0) {
            int p = lc[bk[i]] + rk[i];
            if (p < BCAP) ebuckF[bk[i] * BCAP + p] = pk[i];
        }
}

// ---------------- fused: degree + dinv + rowptr (bucket-local) + CSR col fill ----------------
// rowptr[node] = b*BCAP + in-bucket exclusive scan of (deg-1); valid because
// sum of (deg-1) over a bucket's 256 nodes == the bucket's edge count <= BCAP.

__global__ __launch_bounds__(256) void k_degfill(const int* __restrict__ bcnt,
                                                 const int* __restrict__ ebuckF,
                                                 int* __restrict__ deg,
                                                 float* __restrict__ dinv,
                                                 int* __restrict__ rowptr,
                                                 int* __restrict__ colF) {
    __shared__ int ld[256];
    __shared__ int sA[256];
    __shared__ int lf[256];
    const int b = blockIdx.x, t = threadIdx.x;
    const int cnt = min(bcnt[b], BCAP);
    const int ebase = b * BCAP;
    ld[t] = 1;  // self loop
    __syncthreads();
    for (int j = t; j < cnt; j += 256) atomicAdd(&ld[ebuckF[ebase + j] & 255], 1);
    __syncthreads();
    const int node = (b << BSHIFT) + t;
    const int dg = ld[t];
    if (node < N_NODES) {
        deg[node] = dg;
        dinv[node] = rsqrtf((float)dg);
    }
    const int c = (node < N_NODES) ? dg - 1 : 0;
    sA[t] = c;
    __syncthreads();
    for (int off = 1; off < 256; off <<= 1) {
        int u = (t >= off) ? sA[t - off] : 0;
        __syncthreads();
        sA[t] += u;
        __syncthreads();
    }
    const int pos = ebase + sA[t] - c;  // exclusive scan, bucket-local region
    if (node < N_NODES) rowptr[node] = pos;
    lf[t] = pos;
    __syncthreads();
    for (int j = t; j < cnt; j += 256) {
        int v = ebuckF[ebase + j];
        int p = atomicAdd(&lf[v & 255], 1);
        colF[p] = v >> BSHIFT;
    }
}

// ---------------- MFMA GEMM1: Tb = dinv * (X[fp32] @ W1) ----------------

__global__ __launch_bounds__(256) void k_gemm1(const float* __restrict__ X,
                                               const unsigned short* __restrict__ Wt,
                                               const float* __restrict__ dinv,
                                               unsigned short* __restrict__ Tb) {
    __shared__ unsigned short Wb[64][264];
    const int t = threadIdx.x;
    const int lane = t & 63, wv = t >> 6;
    const int fl = lane & 15, quad = lane >> 4;
    const int r0 = blockIdx.x * 64;

    for (int g = t; g < 64 * 32; g += 256) {
        int n = g >> 5, kc8 = g & 31;
        *(us8*)&Wb[n][kc8 * 8] = *(const us8*)(Wt + n * IN_DIM + kc8 * 8);
    }

    const int arow = r0 + wv * 16 + fl;
    const bool valid = arow < N_NODES;
    const float* xp = X + (size_t)(valid ? arow : 0) * IN_DIM;

    floatx4 acc[4];
#pragma unroll
    for (int j = 0; j < 4; ++j) acc[j] = (floatx4){0.f, 0.f, 0.f, 0.f};

    __syncthreads();

#pragma unroll
    for (int kc = 0; kc < IN_DIM; kc += 32) {
        float4 x0 = make_float4(0.f, 0.f, 0.f, 0.f);
        float4 x1 = make_float4(0.f, 0.f, 0.f, 0.f);
        if (valid) {
            x0 = *(const float4*)(xp + kc + quad * 8);
            x1 = *(const float4*)(xp + kc + quad * 8 + 4);
        }
        short8 a;
        a[0] = (short)f2b(x0.x); a[1] = (short)f2b(x0.y);
        a[2] = (short)f2b(x0.z); a[3] = (short)f2b(x0.w);
        a[4] = (short)f2b(x1.x); a[5] = (short)f2b(x1.y);
        a[6] = (short)f2b(x1.z); a[7] = (short)f2b(x1.w);
#pragma unroll
        for (int ct = 0; ct < 4; ++ct) {
            short8 b = *(const short8*)&Wb[ct * 16 + fl][kc + quad * 8];
            acc[ct] = __builtin_amdgcn_mfma_f32_16x16x32_bf16(a, b, acc[ct], 0, 0, 0);
        }
    }

    int rbase = r0 + wv * 16 + quad * 4;
#pragma unroll
    for (int r = 0; r < 4; ++r) {
        int row = rbase + r;
        if (row < N_NODES) {
            float di = dinv[row];
#pragma unroll
            for (int ct = 0; ct < 4; ++ct)
                Tb[(size_t)row * HID + ct * 16 + fl] = f2b(di * acc[ct][r]);
        }
    }
}

// ---------------- MFMA GEMM2: Tb = dinv * (Hb[bf16] @ W) ----------------

__global__ __launch_bounds__(256) void k_gemm2(const unsigned short* __restrict__ Xin,
                                               const unsigned short* __restrict__ Wt,
                                               const float* __restrict__ dinv,
                                               unsigned short* __restrict__ Tb) {
    __shared__ unsigned short Wb[64][72];
    const int t = threadIdx.x;
    const int lane = t & 63, wv = t >> 6;
    const int fl = lane & 15, quad = lane >> 4;
    const int r0 = blockIdx.x * 64;

    for (int g = t; g < 64 * 8; g += 256) {
        int n = g >> 3, kc8 = g & 7;
        *(us8*)&Wb[n][kc8 * 8] = *(const us8*)(Wt + n * HID + kc8 * 8);
    }

    const int arow = r0 + wv * 16 + fl;
    const bool valid = arow < N_NODES;
    const unsigned short* xp = Xin + (size_t)(valid ? arow : 0) * HID;

    floatx4 acc[4];
#pragma unroll
    for (int j = 0; j < 4; ++j) acc[j] = (floatx4){0.f, 0.f, 0.f, 0.f};

    __syncthreads();

#pragma unroll
    for (int kc = 0; kc < HID; kc += 32) {
        short8 a = (short8){0, 0, 0, 0, 0, 0, 0, 0};
        if (valid) a = *(const short8*)(xp + kc + quad * 8);
#pragma unroll
        for (int ct = 0; ct < 4; ++ct) {
            short8 b = *(const short8*)&Wb[ct * 16 + fl][kc + quad * 8];
            acc[ct] = __builtin_amdgcn_mfma_f32_16x16x32_bf16(a, b, acc[ct], 0, 0, 0);
        }
    }

    int rbase = r0 + wv * 16 + quad * 4;
#pragma unroll
    for (int r = 0; r < 4; ++r) {
        int row = rbase + r;
        if (row < N_NODES) {
            float di = dinv[row];
#pragma unroll
            for (int ct = 0; ct < 4; ++ct)
                Tb[(size_t)row * HID + ct * 16 + fl] = f2b(di * acc[ct][r]);
        }
    }
}

// ---------------- aggregation layer 1: Hb[i] = relu(dinv[i]*(Tb[i]+sum Tb[src])+b) ----
// 1024-thread blocks (16 nodes each), 16-edge unrolled gather for 2x MLP.

__global__ __launch_bounds__(1024) void k_agg(const unsigned short* __restrict__ Tb,
                                              const int* __restrict__ rowptr,
                                              const int* __restrict__ deg,
                                              const float* __restrict__ dinv,
                                              const int* __restrict__ col,
                                              const float* __restrict__ bias,
                                              unsigned short* __restrict__ Hb) {
    int lane = threadIdx.x & 63;
    int node = blockIdx.x * 16 + (threadIdx.x >> 6);
    int grp = lane >> 3, fl = lane & 7;
    int e = __builtin_amdgcn_readfirstlane(rowptr[node]);
    int end = e + __builtin_amdgcn_readfirstlane(deg[node]) - 1;
    float a0 = 0.f, a1 = 0.f, a2 = 0.f, a3 = 0.f;
    float a4 = 0.f, a5 = 0.f, a6 = 0.f, a7 = 0.f;
    for (; e + 16 <= end; e += 16) {
        int s0 = col[e + grp];
        int s1 = col[e + 8 + grp];
        us8 t0 = *(const us8*)(Tb + (size_t)s0 * HID + fl * 8);
        us8 t1 = *(const us8*)(Tb + (size_t)s1 * HID + fl * 8);
        a0 += b2f(t0[0]) + b2f(t1[0]); a1 += b2f(t0[1]) + b2f(t1[1]);
        a2 += b2f(t0[2]) + b2f(t1[2]); a3 += b2f(t0[3]) + b2f(t1[3]);
        a4 += b2f(t0[4]) + b2f(t1[4]); a5 += b2f(t0[5]) + b2f(t1[5]);
        a6 += b2f(t0[6]) + b2f(t1[6]); a7 += b2f(t0[7]) + b2f(t1[7]);
    }
    for (; e + 8 <= end; e += 8) {
        int s = col[e + grp];
        us8 tv = *(const us8*)(Tb + (size_t)s * HID + fl * 8);
        a0 += b2f(tv[0]); a1 += b2f(tv[1]); a2 += b2f(tv[2]); a3 += b2f(tv[3]);
        a4 += b2f(tv[4]); a5 += b2f(tv[5]); a6 += b2f(tv[6]); a7 += b2f(tv[7]);
    }
    if (e + grp < end) {
        int s = col[e + grp];
        us8 tv = *(const us8*)(Tb + (size_t)s * HID + fl * 8);
        a0 += b2f(tv[0]); a1 += b2f(tv[1]); a2 += b2f(tv[2]); a3 += b2f(tv[3]);
        a4 += b2f(tv[4]); a5 += b2f(tv[5]); a6 += b2f(tv[6]); a7 += b2f(tv[7]);
    }
    a0 += __shfl_xor(a0, 8);  a1 += __shfl_xor(a1, 8);
    a2 += __shfl_xor(a2, 8);  a3 += __shfl_xor(a3, 8);
    a4 += __shfl_xor(a4, 8);  a5 += __shfl_xor(a5, 8);
    a6 += __shfl_xor(a6, 8);  a7 += __shfl_xor(a7, 8);
    a0 += __shfl_xor(a0, 16); a1 += __shfl_xor(a1, 16);
    a2 += __shfl_xor(a2, 16); a3 += __shfl_xor(a3, 16);
    a4 += __shfl_xor(a4, 16); a5 += __shfl_xor(a5, 16);
    a6 += __shfl_xor(a6, 16); a7 += __shfl_xor(a7, 16);
    a0 += __shfl_xor(a0, 32); a1 += __shfl_xor(a1, 32);
    a2 += __shfl_xor(a2, 32); a3 += __shfl_xor(a3, 32);
    a4 += __shfl_xor(a4, 32); a5 += __shfl_xor(a5, 32);
    a6 += __shfl_xor(a6, 32); a7 += __shfl_xor(a7, 32);
    us8 sv = *(const us8*)(Tb + (size_t)node * HID + fl * 8);
    a0 += b2f(sv[0]); a1 += b2f(sv[1]); a2 += b2f(sv[2]); a3 += b2f(sv[3]);
    a4 += b2f(sv[4]); a5 += b2f(sv[5]); a6 += b2f(sv[6]); a7 += b2f(sv[7]);
    float di = dinv[node];
    float4 b0 = *(const float4*)(bias + fl * 8);
    float4 b1v = *(const float4*)(bias + fl * 8 + 4);
    a0 = fmaxf(fmaf(di, a0, b0.x), 0.f);
    a1 = fmaxf(fmaf(di, a1, b0.y), 0.f);
    a2 = fmaxf(fmaf(di, a2, b0.z), 0.f);
    a3 = fmaxf(fmaf(di, a3, b0.w), 0.f);
    a4 = fmaxf(fmaf(di, a4, b1v.x), 0.f);
    a5 = fmaxf(fmaf(di, a5, b1v.y), 0.f);
    a6 = fmaxf(fmaf(di, a6, b1v.z), 0.f);
    a7 = fmaxf(fmaf(di, a7, b1v.w), 0.f);
    if (grp == 0) {
        us8 o;
        o[0] = f2b(a0); o[1] = f2b(a1); o[2] = f2b(a2); o[3] = f2b(a3);
        o[4] = f2b(a4); o[5] = f2b(a5); o[6] = f2b(a6); o[7] = f2b(a7);
        *(us8*)(Hb + (size_t)node * HID + fl * 8) = o;
    }
}

// ---------------- aggregation layer 2 fused with layer-3 GEMV ----------------

__global__ __launch_bounds__(1024) void k_agg_z(const unsigned short* __restrict__ Tb,
                                                const int* __restrict__ rowptr,
                                                const int* __restrict__ deg,
                                                const float* __restrict__ dinv,
                                                const int* __restrict__ col,
                                                const float* __restrict__ bias,
                                                const float* __restrict__ w3l,
                                                float* __restrict__ z) {
    int lane = threadIdx.x & 63;
    int node = blockIdx.x * 16 + (threadIdx.x >> 6);
    int grp = lane >> 3, fl = lane & 7;
    int e = __builtin_amdgcn_readfirstlane(rowptr[node]);
    int end = e + __builtin_amdgcn_readfirstlane(deg[node]) - 1;
    float a0 = 0.f, a1 = 0.f, a2 = 0.f, a3 = 0.f;
    float a4 = 0.f, a5 = 0.f, a6 = 0.f, a7 = 0.f;
    for (; e + 16 <= end; e += 16) {
        int s0 = col[e + grp];
        int s1 = col[e + 8 + grp];
        us8 t0 = *(const us8*)(Tb + (size_t)s0 * HID + fl * 8);
        us8 t1 = *(const us8*)(Tb + (size_t)s1 * HID + fl * 8);
        a0 += b2f(t0[0]) + b2f(t1[0]); a1 += b2f(t0[1]) + b2f(t1[1]);
        a2 += b2f(t0[2]) + b2f(t1[2]); a3 += b2f(t0[3]) + b2f(t1[3]);
        a4 += b2f(t0[4]) + b2f(t1[4]); a5 += b2f(t0[5]) + b2f(t1[5]);
        a6 += b2f(t0[6]) + b2f(t1[6]); a7 += b2f(t0[7]) + b2f(t1[7]);
    }
    for (; e + 8 <= end; e += 8) {
        int s = col[e + grp];
        us8 tv = *(const us8*)(Tb + (size_t)s * HID + fl * 8);
        a0 += b2f(tv[0]); a1 += b2f(tv[1]); a2 += b2f(tv[2]); a3 += b2f(tv[3]);
        a4 += b2f(tv[4]); a5 += b2f(tv[5]); a6 += b2f(tv[6]); a7 += b2f(tv[7]);
    }
    if (e + grp < end) {
        int s = col[e + grp];
        us8 tv = *(const us8*)(Tb + (size_t)s * HID + fl * 8);
        a0 += b2f(tv[0]); a1 += b2f(tv[1]); a2 += b2f(tv[2]); a3 += b2f(tv[3]);
        a4 += b2f(tv[4]); a5 += b2f(tv[5]); a6 += b2f(tv[6]); a7 += b2f(tv[7]);
    }
    a0 += __shfl_xor(a0, 8);  a1 += __shfl_xor(a1, 8);
    a2 += __shfl_xor(a2, 8);  a3 += __shfl_xor(a3, 8);
    a4 += __shfl_xor(a4, 8);  a5 += __shfl_xor(a5, 8);
    a6 += __shfl_xor(a6, 8);  a7 += __shfl_xor(a7, 8);
    a0 += __shfl_xor(a0, 16); a1 += __shfl_xor(a1, 16);
    a2 += __shfl_xor(a2, 16); a3 += __shfl_xor(a3, 16);
    a4 += __shfl_xor(a4, 16); a5 += __shfl_xor(a5, 16);
    a6 += __shfl_xor(a6, 16); a7 += __shfl_xor(a7, 16);
    a0 += __shfl_xor(a0, 32); a1 += __shfl_xor(a1, 32);
    a2 += __shfl_xor(a2, 32); a3 += __shfl_xor(a3, 32);
    a4 += __shfl_xor(a4, 32); a5 += __shfl_xor(a5, 32);
    a6 += __shfl_xor(a6, 32); a7 += __shfl_xor(a7, 32);
    us8 sv = *(const us8*)(Tb + (size_t)node * HID + fl * 8);
    a0 += b2f(sv[0]); a1 += b2f(sv[1]); a2 += b2f(sv[2]); a3 += b2f(sv[3]);
    a4 += b2f(sv[4]); a5 += b2f(sv[5]); a6 += b2f(sv[6]); a7 += b2f(sv[7]);
    float di = dinv[node];
    float4 b0 = *(const float4*)(bias + fl * 8);
    float4 b1v = *(const float4*)(bias + fl * 8 + 4);
    a0 = fmaxf(fmaf(di, a0, b0.x), 0.f);
    a1 = fmaxf(fmaf(di, a1, b0.y), 0.f);
    a2 = fmaxf(fmaf(di, a2, b0.z), 0.f);
    a3 = fmaxf(fmaf(di, a3, b0.w), 0.f);
    a4 = fmaxf(fmaf(di, a4, b1v.x), 0.f);
    a5 = fmaxf(fmaf(di, a5, b1v.y), 0.f);
    a6 = fmaxf(fmaf(di, a6, b1v.z), 0.f);
    a7 = fmaxf(fmaf(di, a7, b1v.w), 0.f);
    // fused layer-3 GEMV: lanes of each 8-group jointly hold the full reduced row
    float4 w0 = *(const float4*)(w3l + fl * 8);
    float4 w1v = *(const float4*)(w3l + fl * 8 + 4);
    float s = a0 * w0.x + a1 * w0.y + a2 * w0.z + a3 * w0.w +
              a4 * w1v.x + a5 * w1v.y + a6 * w1v.z + a7 * w1v.w;
    s += __shfl_xor(s, 1);
    s += __shfl_xor(s, 2);
    s += __shfl_xor(s, 4);
    if (lane == 0) z[node] = di * s;
}

// scalar aggregation + pool: partial[g][blk] += b3wl + dinv[d]*(z[d] + sum z[src])
__global__ __launch_bounds__(256) void k_aggpool_s(const float* __restrict__ z,
                                                   const int* __restrict__ rowptr,
                                                   const int* __restrict__ deg,
                                                   const float* __restrict__ dinv,
                                                   const int* __restrict__ col,
                                                   const float* __restrict__ w3l,
                                                   const int* __restrict__ batch,
                                                   float* __restrict__ partial) {
    int i = blockIdx.x * 256 + threadIdx.x;
    if (i >= N_NODES) return;
    int e = rowptr[i];
    int end = e + deg[i] - 1;
    float s0 = z[i], s1 = 0.f, s2 = 0.f, s3 = 0.f;
    for (; e + 4 <= end; e += 4) {
        s0 += z[col[e]];
        s1 += z[col[e + 1]];
        s2 += z[col[e + 2]];
        s3 += z[col[e + 3]];
    }
    for (; e < end; ++e) s0 += z[col[e]];
    float s = w3l[HID] + dinv[i] * (s0 + s1 + s2 + s3);
    atomicAdd(&partial[batch[i] * 256 + (blockIdx.x & 255)], s);
}

__global__ void k_pool_reduce(const float* __restrict__ partial,
                              const float* __restrict__ bl,
                              float* __restrict__ out) {
    int g = blockIdx.x, t = threadIdx.x;
    float s = partial[g * 256 + t];
    s += __shfl_xor(s, 32);
    s += __shfl_xor(s, 16);
    s += __shfl_xor(s, 8);
    s += __shfl_xor(s, 4);
    s += __shfl_xor(s, 2);
    s += __shfl_xor(s, 1);
    __shared__ float ws[4];
    if ((t & 63) == 0) ws[t >> 6] = s;
    __syncthreads();
    if (t == 0) out[g] = bl[0] + ws[0] + ws[1] + ws[2] + ws[3];
}

extern "C" void kernel_launch(void* const* d_in, const int* in_sizes, int n_in,
                              void* d_out, int out_size, void* d_ws, size_t ws_size,
                              hipStream_t stream) {
    const float* x     = (const float*)d_in[0];
    const int*   ei    = (const int*)d_in[1];
    const int*   batch = (const int*)d_in[2];
    const float* W1    = (const float*)d_in[3];
    const float* b1    = (const float*)d_in[4];
    const float* W2    = (const float*)d_in[5];
    const float* b2    = (const float*)d_in[6];
    const float* W3    = (const float*)d_in[7];
    const float* b3    = (const float*)d_in[8];
    const float* Wl    = (const float*)d_in[9];
    const float* bl    = (const float*)d_in[10];
    float* out = (float*)d_out;

    char* p = (char*)d_ws;
    unsigned short* tb = (unsigned short*)p; p += (size_t)N_NODES * HID * 2;  // 12.8 MB
    unsigned short* hB = (unsigned short*)p; p += (size_t)N_NODES * HID * 2;  // 12.8 MB
    int*   colF    = (int*)p;   p += (size_t)NBUCK * BCAP * 4;                // 8.0 MB
    int*   ebuckF  = (int*)p;   p += (size_t)NBUCK * BCAP * 4;                // 8.0 MB
    int*   deg     = (int*)p;   p += (size_t)N_NODES * 4;
    float* dinv    = (float*)p; p += (size_t)N_NODES * 4;
    int*   rowptr  = (int*)p;   p += (size_t)N_NODES * 4;
    float* z       = (float*)p; p += (size_t)N_NODES * 4;
    int*   bcnt    = (int*)p;   p += (NBUCK + 1) * 4;
    float* partial = (float*)p; p += (size_t)N_GRAPHS * 256 * 4;
    unsigned short* wt1 = (unsigned short*)p; p += (size_t)IN_DIM * HID * 2;
    unsigned short* wt2 = (unsigned short*)p; p += (size_t)HID * HID * 2;
    float* w3l     = (float*)p; p += 128 * 4;   // w3l[64] + b3wl at [64]

    const int* src  = ei;
    const int* dstp = ei + N_EDGES;

    const int nb = (N_NODES + 255) / 256;            // 391
    const int cb = (N_EDGES + CHUNK - 1) / CHUNK;    // 391
    const int gemm_blocks = (N_NODES + 63) / 64;     // 1563
    const int agg_blocks = (N_NODES + 15) / 16;      // 6250

    k_prep<<<128, 256, 0, stream>>>(W1, W2, W3, Wl, b3, wt1, wt2, w3l, bcnt, partial);
    k_scatter<<<cb, 256, 0, stream>>>(src, dstp, bcnt, ebuckF);
    k_degfill<<<NBUCK, 256, 0, stream>>>(bcnt, ebuckF, deg, dinv, rowptr, colF);

    k_gemm1<<<gemm_blocks, 256, 0, stream>>>(x, wt1, dinv, tb);
    k_agg<<<agg_blocks, 1024, 0, stream>>>(tb, rowptr, deg, dinv, colF, b1, hB);
    k_gemm2<<<gemm_blocks, 256, 0, stream>>>(hB, wt2, dinv, tb);
    k_agg_z<<<agg_blocks, 1024, 0, stream>>>(tb, rowptr, deg, dinv, colF, b2, w3l, z);

    k_aggpool_s<<<nb, 256, 0, stream>>>(z, rowptr, deg, dinv, colF, w3l, batch, partial);
    k_pool_reduce<<<N_GRAPHS, 256, 0, stream>>>(partial, bl, out);
}